// Round 3
// baseline (295.703 us; speedup 1.0000x reference)
//
#include <hip/hip_runtime.h>

#define EPSV 1e-5f

typedef __attribute__((ext_vector_type(8))) short short8;
typedef __attribute__((ext_vector_type(4))) float f32x4;
typedef unsigned short ushort_t;

__device__ inline ushort_t f2bf(float f) {
    unsigned int x = __builtin_bit_cast(unsigned int, f);
    unsigned int r = (x + 0x7fffu + ((x >> 16) & 1u)) >> 16;
    return (ushort_t)r;
}
__device__ inline float bf2f(ushort_t u) {
    return __builtin_bit_cast(float, (unsigned int)u << 16);
}

// ---- weight prep (blocks 0..591) + time embedding (block 592) ----
__global__ __launch_bounds__(256) void k_prep(
    const float* __restrict__ w_fuse, const float* __restrict__ w3,
    const float* __restrict__ wup,
    const float* __restrict__ tin, const float* __restrict__ w_temb,
    const float* __restrict__ b_temb, float* __restrict__ emb,
    ushort_t* __restrict__ wfuset, ushort_t* __restrict__ w3t, ushort_t* __restrict__ wupt) {
    if (blockIdx.x == 592) {
        __shared__ float st[8 * 256];
        int t = threadIdx.x;
        for (int i = t; i < 2048; i += 256) { float v = tin[i]; st[i] = v / (1.f + __expf(-v)); }
        __syncthreads();
        for (int p = t; p < 512; p += 256) {
            int bb = p >> 6, c = p & 63;
            float acc = b_temb[c];
            for (int e = 0; e < 256; e++) acc += st[bb * 256 + e] * w_temb[e * 64 + c];
            emb[bb * 64 + c] = acc;
        }
        return;
    }
    int i = blockIdx.x * 256 + threadIdx.x;
    if (i < 8192) {
        int cout = i >> 7, cin = i & 127;
        wfuset[i] = f2bf(w_fuse[cin * 64 + cout]);
    } else if (i < 8192 + 110592) {
        int j = i - 8192;
        int k = j >> 12, r = j & 4095, cout = r >> 6, cin = r & 63;
        w3t[j] = f2bf(w3[k * 4096 + cin * 64 + cout]);
    } else if (i < 151552) {
        int j = i - 118784;
        int k = j >> 12, r = j & 4095, f = r >> 6, c = r & 63;
        wupt[j] = f2bf(wup[k * 4096 + c * 64 + f]);
    }
}

// ---- K1: T(bf16) = feats @ w_fuse, + BN1 partials. Wave w owns cols w*16+ln. ----
__global__ __launch_bounds__(256) void k_gemm_fuse(
    const float* __restrict__ feats, const ushort_t* __restrict__ wfuset,
    ushort_t* __restrict__ T, float* __restrict__ partial, int npts) {
    __shared__ ushort_t A[64 * 136];
    int t = threadIdx.x, bid = blockIdx.x;
    int lane = t & 63, w = t >> 6, q = lane >> 4, ln = lane & 15;
    int nbase = bid * 64;
    for (int i = 0; i < 4; i++) {
        int slot = i * 256 + t;
        int row = slot >> 4, seg = slot & 15;
        int n = nbase + row;
        short8 val = (short8)0;
        if (n < npts) {
            const float* src = feats + (size_t)n * 128 + seg * 8;
            float4 a = *(const float4*)(src);
            float4 b = *(const float4*)(src + 4);
            ushort_t u[8] = {f2bf(a.x), f2bf(a.y), f2bf(a.z), f2bf(a.w),
                             f2bf(b.x), f2bf(b.y), f2bf(b.z), f2bf(b.w)};
            val = *(short8*)u;
        }
        *(short8*)&A[row * 136 + seg * 8] = val;
    }
    __syncthreads();
    f32x4 acc[4];
    for (int i = 0; i < 4; i++) acc[i] = (f32x4)0.f;
    int col = w * 16 + ln;
    for (int s = 0; s < 4; s++) {
        short8 bfr = *(const short8*)&wfuset[col * 128 + s * 32 + q * 8];
        for (int i = 0; i < 4; i++) {
            short8 afr = *(const short8*)&A[(i * 16 + ln) * 136 + s * 32 + q * 8];
            acc[i] = __builtin_amdgcn_mfma_f32_16x16x32_bf16(afr, bfr, acc[i], 0, 0, 0);
        }
    }
    float ps = 0.f, pq = 0.f;
    for (int i = 0; i < 4; i++)
        for (int r = 0; r < 4; r++) {
            float v = acc[i][r];
            int row = nbase + i * 16 + q * 4 + r;
            if (row < npts) T[(size_t)row * 64 + col] = f2bf(v);
            ps += v; pq += v * v;
        }
    ps += __shfl_xor(ps, 16); ps += __shfl_xor(ps, 32);
    pq += __shfl_xor(pq, 16); pq += __shfl_xor(pq, 32);
    if (lane < 16) {
        partial[(size_t)bid * 128 + col] = ps;
        partial[(size_t)bid * 128 + 64 + col] = pq;
    }
}

// ---- finalize BN: coalesced float4 streaming reduce ----
__global__ __launch_bounds__(1024) void k_finalize(
    const float* __restrict__ partial, int nrows, float inv_count,
    const float* __restrict__ g, const float* __restrict__ b, float* __restrict__ prm) {
    __shared__ float red[32][128];
    __shared__ float fin[128];
    int t = threadIdx.x;
    int lanec = t & 31;   // float4 column: channels lanec*4..+3 of the 128-wide row
    int grp = t >> 5;     // 32 row-groups
    float4 a4 = {0.f, 0.f, 0.f, 0.f};
    for (int r = grp; r < nrows; r += 32) {
        float4 v = *(const float4*)&partial[(size_t)r * 128 + lanec * 4];
        a4.x += v.x; a4.y += v.y; a4.z += v.z; a4.w += v.w;
    }
    red[grp][lanec * 4 + 0] = a4.x;
    red[grp][lanec * 4 + 1] = a4.y;
    red[grp][lanec * 4 + 2] = a4.z;
    red[grp][lanec * 4 + 3] = a4.w;
    __syncthreads();
    if (t < 128) {
        float s = 0.f;
        for (int i = 0; i < 32; i++) s += red[i][t];
        fin[t] = s;
    }
    __syncthreads();
    if (t < 64) {
        float mean = fin[t] * inv_count;
        float var = fin[64 + t] * inv_count - mean * mean;
        float scale = g[t] * rsqrtf(var + EPSV);
        prm[t] = scale;
        prm[64 + t] = b[t] - mean * scale;
    }
}

// ---- apply BN1 + ReLU + emb -> h (bf16) ----
__global__ __launch_bounds__(256) void k_apply1(
    const ushort_t* __restrict__ T, const float* __restrict__ prm,
    const float* __restrict__ emb, const int* __restrict__ bidx,
    ushort_t* __restrict__ h, int npts) {
    int tid = blockIdx.x * 256 + threadIdx.x;
    if (tid >= npts * 8) return;
    int row = tid >> 3, c0 = (tid & 7) * 8;
    int bi = bidx[row];
    short8 x = *(const short8*)&T[(size_t)row * 64 + c0];
    ushort_t o[8];
#pragma unroll
    for (int j = 0; j < 8; j++) {
        int c = c0 + j;
        float v = prm[c] * bf2f((ushort_t)x[j]) + prm[64 + c];
        v = fmaxf(v, 0.f) + emb[bi * 64 + c];
        o[j] = f2bf(v);
    }
    *(short8*)&h[(size_t)row * 64 + c0] = *(short8*)o;
}

// ---- K4: 27-offset gather-GEMM, register-direct, idx prefetched in chunks of 9 ----
__global__ __launch_bounds__(256) void k_conv27(
    const ushort_t* __restrict__ h, const ushort_t* __restrict__ w3t,
    const int* __restrict__ nbr,
    ushort_t* __restrict__ out2, float* __restrict__ partial, int npts) {
    int t = threadIdx.x, bid = blockIdx.x;
    int lane = t & 63, w = t >> 6, q = lane >> 4, ln = lane & 15;
    int nbase = bid * 64;
    int col = w * 16 + ln;
    f32x4 acc[4];
    for (int i = 0; i < 4; i++) acc[i] = (f32x4)0.f;
    int rowi[4];
    bool rv[4];
    for (int i = 0; i < 4; i++) { rowi[i] = nbase + i * 16 + ln; rv[i] = rowi[i] < npts; }
    for (int kc = 0; kc < 27; kc += 9) {
        int idx[9][4];
#pragma unroll
        for (int k2 = 0; k2 < 9; k2++) {
            const int* nb = nbr + (size_t)(kc + k2) * npts;
#pragma unroll
            for (int i = 0; i < 4; i++) idx[k2][i] = rv[i] ? nb[rowi[i]] : -1;
        }
#pragma unroll
        for (int k2 = 0; k2 < 9; k2++) {
            int k = kc + k2;
            short8 bfr0 = *(const short8*)&w3t[(size_t)k * 4096 + col * 64 + q * 8];
            short8 bfr1 = *(const short8*)&w3t[(size_t)k * 4096 + col * 64 + 32 + q * 8];
            for (int i = 0; i < 4; i++) {
                if (__any(idx[k2][i] >= 0)) {
                    short8 a0 = (short8)0, a1 = (short8)0;
                    if (idx[k2][i] >= 0) {
                        const ushort_t* hp = h + (size_t)idx[k2][i] * 64 + q * 8;
                        a0 = *(const short8*)hp;
                        a1 = *(const short8*)(hp + 32);
                    }
                    acc[i] = __builtin_amdgcn_mfma_f32_16x16x32_bf16(a0, bfr0, acc[i], 0, 0, 0);
                    acc[i] = __builtin_amdgcn_mfma_f32_16x16x32_bf16(a1, bfr1, acc[i], 0, 0, 0);
                }
            }
        }
    }
    float ps = 0.f, pq = 0.f;
    for (int i = 0; i < 4; i++)
        for (int r = 0; r < 4; r++) {
            float v = acc[i][r];
            int row = nbase + i * 16 + q * 4 + r;
            ps += v; pq += v * v;
            if (row < npts) out2[(size_t)row * 64 + col] = f2bf(v);
        }
    ps += __shfl_xor(ps, 16); ps += __shfl_xor(ps, 32);
    pq += __shfl_xor(pq, 16); pq += __shfl_xor(pq, 32);
    if (lane < 16) {
        partial[(size_t)bid * 128 + col] = ps;
        partial[(size_t)bid * 128 + 64 + col] = pq;
    }
}

// ---- apply BN2+ReLU -> h2, and fused up-projection STATS (no output write) ----
__global__ __launch_bounds__(256) void k_apply2up(
    const ushort_t* __restrict__ out2, const float* __restrict__ prm2,
    const ushort_t* __restrict__ wupt,
    ushort_t* __restrict__ h2, float* __restrict__ partial, int npts) {
    __shared__ ushort_t A[64 * 72];
    int t = threadIdx.x, bid = blockIdx.x;
    int lane = t & 63, w = t >> 6, q = lane >> 4, ln = lane & 15;
    int nbase = bid * 64;
    for (int i2 = 0; i2 < 2; i2++) {
        int slot = i2 * 256 + t;
        int row = slot >> 3, seg = slot & 7;
        int n = nbase + row;
        short8 val = (short8)0;
        if (n < npts) {
            short8 x = *(const short8*)&out2[(size_t)n * 64 + seg * 8];
            ushort_t o[8];
#pragma unroll
            for (int j = 0; j < 8; j++) {
                int c = seg * 8 + j;
                float v = prm2[c] * bf2f((ushort_t)x[j]) + prm2[64 + c];
                o[j] = f2bf(fmaxf(v, 0.f));
            }
            val = *(short8*)o;
            *(short8*)&h2[(size_t)n * 64 + seg * 8] = val;
        }
        *(short8*)&A[row * 72 + seg * 8] = val;
    }
    __syncthreads();
    int col = w * 16 + ln;
    short8 afr[4][2];
    for (int i = 0; i < 4; i++)
        for (int s = 0; s < 2; s++)
            afr[i][s] = *(const short8*)&A[(i * 16 + ln) * 72 + s * 32 + q * 8];
    float ps = 0.f, pq = 0.f;
    for (int uk = 0; uk < 8; uk++) {
        f32x4 acc[4];
        for (int i = 0; i < 4; i++) acc[i] = (f32x4)0.f;
        for (int s = 0; s < 2; s++) {
            short8 bfr = *(const short8*)&wupt[(size_t)uk * 4096 + col * 64 + s * 32 + q * 8];
            for (int i = 0; i < 4; i++)
                acc[i] = __builtin_amdgcn_mfma_f32_16x16x32_bf16(afr[i][s], bfr, acc[i], 0, 0, 0);
        }
        for (int i = 0; i < 4; i++)
            for (int r = 0; r < 4; r++) { float v = acc[i][r]; ps += v; pq += v * v; }
    }
    ps += __shfl_xor(ps, 16); ps += __shfl_xor(ps, 32);
    pq += __shfl_xor(pq, 16); pq += __shfl_xor(pq, 32);
    if (lane < 16) {
        partial[(size_t)bid * 128 + col] = ps;
        partial[(size_t)bid * 128 + 64 + col] = pq;
    }
}

// ---- final up-projection: row-owning waves, BN3 + ReLU + coalesced-ish store ----
__global__ __launch_bounds__(256) void k_up(
    const ushort_t* __restrict__ h2, const ushort_t* __restrict__ wupt,
    const float* __restrict__ prm3, float* __restrict__ outp, int npts) {
    int t = threadIdx.x, bid = blockIdx.x;
    int lane = t & 63, w = t >> 6, q = lane >> 4, ln = lane & 15;
    int rbase = bid * 64 + w * 16;   // wave owns rows rbase..rbase+15, all 64 cols
    int row = rbase + ln;
    short8 afr[2];
    for (int s = 0; s < 2; s++)
        afr[s] = (row < npts) ? *(const short8*)&h2[(size_t)row * 64 + s * 32 + q * 8]
                              : (short8)0;
    float sc[4], sh[4];
#pragma unroll
    for (int j = 0; j < 4; j++) { sc[j] = prm3[j * 16 + ln]; sh[j] = prm3[64 + j * 16 + ln]; }
    for (int uk = 0; uk < 8; uk++) {
        f32x4 acc[4];
        for (int j = 0; j < 4; j++) acc[j] = (f32x4)0.f;
        for (int s = 0; s < 2; s++) {
            short8 a = afr[s];
            for (int j = 0; j < 4; j++) {
                short8 bfr = *(const short8*)&wupt[(size_t)uk * 4096 + (j * 16 + ln) * 64 + s * 32 + q * 8];
                acc[j] = __builtin_amdgcn_mfma_f32_16x16x32_bf16(a, bfr, acc[j], 0, 0, 0);
            }
        }
#pragma unroll
        for (int r = 0; r < 4; r++) {
            int rr = rbase + q * 4 + r;
            if (rr < npts) {
                float* dst = outp + ((size_t)rr * 8 + uk) * 64;
#pragma unroll
                for (int j = 0; j < 4; j++)
                    dst[j * 16 + ln] = fmaxf(sc[j] * acc[j][r] + sh[j], 0.f);
            }
        }
    }
}

extern "C" void kernel_launch(void* const* d_in, const int* in_sizes, int n_in,
                              void* d_out, int out_size, void* d_ws, size_t ws_size,
                              hipStream_t stream) {
    const float* feats  = (const float*)d_in[0];
    const float* tin    = (const float*)d_in[1];
    const float* w_fuse = (const float*)d_in[2];
    const float* g1     = (const float*)d_in[3];
    const float* b1     = (const float*)d_in[4];
    const float* w_temb = (const float*)d_in[5];
    const float* b_temb = (const float*)d_in[6];
    const float* w3     = (const float*)d_in[7];
    const float* g2     = (const float*)d_in[8];
    const float* b2     = (const float*)d_in[9];
    const float* wup    = (const float*)d_in[10];
    const float* g3     = (const float*)d_in[11];
    const float* b3     = (const float*)d_in[12];
    const int* bidx     = (const int*)d_in[13];
    const int* nbr      = (const int*)d_in[14];

    int npts = in_sizes[13];  // N = 100000
    float* dout = (float*)d_out;

    // d_out doubles as scratch (all dead before the final full write):
    char* ob = (char*)d_out;
    ushort_t* T     = (ushort_t*)ob;                               // 12.8 MB
    ushort_t* h     = (ushort_t*)(ob + (size_t)npts * 128);        // 12.8 MB
    ushort_t* out2  = (ushort_t*)(ob + (size_t)npts * 256);        // 12.8 MB

    char* ws = (char*)d_ws;
    float* partial    = (float*)ws;                           // 1563*128 f32
    float* prm        = (float*)(ws + 1048576);               // 3 x [scale64|shift64]
    float* emb        = (float*)(ws + 1048576 + 4096);        // 8 x 64
    ushort_t* wfuset  = (ushort_t*)(ws + 1048576 + 8192);
    ushort_t* w3t     = (ushort_t*)(ws + 1048576 + 8192 + 16384);
    ushort_t* wupt    = (ushort_t*)(ws + 1048576 + 8192 + 16384 + 221184);
    ushort_t* h2      = (ushort_t*)(ws + 1048576 + 8192 + 16384 + 221184 + 65536);

    int nblk = (npts + 63) / 64;  // 1563
    int napp = (npts * 8 + 255) / 256;

    k_prep<<<593, 256, 0, stream>>>(w_fuse, w3, wup, tin, w_temb, b_temb, emb,
                                    wfuset, w3t, wupt);
    k_gemm_fuse<<<nblk, 256, 0, stream>>>(feats, wfuset, T, partial, npts);
    k_finalize<<<1, 1024, 0, stream>>>(partial, nblk, 1.f / npts, g1, b1, prm);
    k_apply1<<<napp, 256, 0, stream>>>(T, prm, emb, bidx, h, npts);
    k_conv27<<<nblk, 256, 0, stream>>>(h, w3t, nbr, out2, partial, npts);
    k_finalize<<<1, 1024, 0, stream>>>(partial, nblk, 1.f / npts, g2, b2, prm + 128);
    k_apply2up<<<nblk, 256, 0, stream>>>(out2, prm + 128, wupt, h2, partial, npts);
    k_finalize<<<1, 1024, 0, stream>>>(partial, nblk, 1.f / (8.f * npts), g3, b3, prm + 256);
    k_up<<<nblk, 256, 0, stream>>>(h2, wupt, prm + 256, dout, npts);
}